// Round 5
// baseline (690.006 us; speedup 1.0000x reference)
//
#include <hip/hip_runtime.h>

typedef unsigned short u16;
typedef unsigned int u32;
typedef u16 us8 __attribute__((ext_vector_type(8)));
typedef __bf16 bf16x8 __attribute__((ext_vector_type(8)));
typedef float f32x4 __attribute__((ext_vector_type(4)));
typedef u32 u32x2 __attribute__((ext_vector_type(2)));
typedef u32 u32x4 __attribute__((ext_vector_type(4)));

constexpr int kE = 8;
constexpr int kHID = 2048;    // K of GEMM1, N of GEMM2
constexpr int kINTER = 1408;  // N of GEMM1, K of GEMM2
constexpr int kTOT = 8192;

// fp32 -> bf16 round-to-nearest-even
static __device__ __forceinline__ u16 f2bf(float f) {
  u32 u = __float_as_uint(f);
  u32 r = (u + 0x7fffu + ((u >> 16) & 1u)) >> 16;
  return (u16)r;
}

// async global->LDS; LDS dest = wave-uniform base, HW adds lane*16B
static __device__ __forceinline__ void gll16(const u16* g, u16* l) {
  __builtin_amdgcn_global_load_lds(
      (const __attribute__((address_space(1))) u32*)g,
      (__attribute__((address_space(3))) u32*)l, 16, 0, 0);
}

// raw LDS byte offset of a generic pointer into shared memory
static __device__ __forceinline__ u32 lds_off(u16* p) {
  return (u32)(uintptr_t)(__attribute__((address_space(3))) u16*)p;
}

// hardware transpose read: 16-lane group covers a 4x16 bf16 row-major block
// (lane addr = groupbase + (l&15)*8B); lane receives column (l&15), elems in
// row (=k) order. OFF walks subtiles (+1024B = next 4-k subtile).
template <int OFF>
static __device__ __forceinline__ u32x2 trr(u32 va) {
  u32x2 d;
  asm volatile("ds_read_b64_tr_b16 %0, %1 offset:%2"
               : "=v"(d) : "v"(va), "i"(OFF));
  return d;
}

static __device__ __forceinline__ bf16x8 mkfrag(u32x2 lo, u32x2 hi) {
  u32x4 c = {lo[0], lo[1], hi[0], hi[1]};
  return __builtin_bit_cast(bf16x8, c);
}

// ---------------- pre-pass: fp32 -> bf16 streaming convert (X and all W) ----------------
__global__ void conv_bf16(const float* __restrict__ x, u16* __restrict__ o) {
  size_t i = ((size_t)blockIdx.x * 256 + threadIdx.x) * 8;
  const float4* p = (const float4*)(x + i);
  float4 f0 = p[0], f1 = p[1];
  us8 v;
  v[0] = f2bf(f0.x); v[1] = f2bf(f0.y); v[2] = f2bf(f0.z); v[3] = f2bf(f0.w);
  v[4] = f2bf(f1.x); v[5] = f2bf(f1.y); v[6] = f2bf(f1.z); v[7] = f2bf(f1.w);
  *(us8*)(o + i) = v;
}

// -------- expert lookup: flat 256-row m-supertile -> (expert, row range) --------
static __device__ __forceinline__ bool expert_of_tile256(
    const int* __restrict__ tpe, int ty, int& e, int& m0, int& m_end) {
  int tile_base = 0, row_base = 0;
  e = -1;
  for (int i = 0; i < kE; i++) {
    int tc = tpe[i];
    int nt = (tc + 255) >> 8;
    if (e < 0 && ty < tile_base + nt) {
      e = i;
      m0 = row_base + (ty - tile_base) * 256;
      m_end = row_base + tc;
    }
    tile_base += nt;
    row_base += tc;
  }
  return e >= 0;
}

// -------- T1: bijective XCD chunking (m204) + GROUP-4 m-supertile decode --------
static __device__ __forceinline__ void map_block(int& bx, int& by) {
  int nx = gridDim.x, ny = gridDim.y;
  int nwg = nx * ny;
  int flat = blockIdx.y * nx + blockIdx.x;
  int q = nwg >> 3, r = nwg & 7;
  int xcd = flat & 7, lid = flat >> 3;
  int nf = (xcd < r ? xcd * (q + 1) : r * (q + 1) + (xcd - r) * q) + lid;
  const int G = 4;
  int gs = G * nx;
  int grp = nf / gs;
  int wi = nf - grp * gs;
  int rows = ny - grp * G;
  if (rows > G) rows = G;
  bx = wi / rows;
  by = grp * G + (wi - bx * rows);
}

// ---------------- GEMM1: 256x128 tile, BK=64, 8 waves (4Mx2N), gate+up fused ----------------
// Same verified R1/R3 sync skeleton. A-path identical (XOR swizzle, gll16).
// B-path NEW: W stays [K][N] bf16; staged as 4x16 row-major subtiles
// (subtile (kb,nb) at byte (kb*8+nb)*128 within 16KB panel); fragments via
// ds_read_b64_tr_b16 pairs. No weight transpose prepass.
__launch_bounds__(512, 2)
__global__ void gemm1(const u16* __restrict__ Xb, const u16* __restrict__ Wgb,
                      const u16* __restrict__ Wub, const float* __restrict__ probs,
                      const int* __restrict__ tpe, u16* __restrict__ H) {
  __shared__ __align__(16) u16 sm[65536];  // 128 KB
  // u16 offsets: A0 0 | A1 16384 | Bg0 32768 | Bg1 40960 | Bu0 49152 | Bu1 57344

  int bx, by; map_block(bx, by);
  int e, m0, m_end;
  if (!expert_of_tile256(tpe, by, e, m0, m_end)) return;
  int n0 = bx * 128;

  int t = threadIdx.x;
  int w = t >> 6, lane = t & 63;
  int quad = lane >> 4, l15 = lane & 15;
  int wm = (w >> 1) * 64, wn = (w & 1) * 64;

  // ---- A staging (verified): 64 rows x 128B per round, XOR-swizzled source chunk ----
  int trow = t >> 3;
  int cg = (t & 7) ^ (trow & 7);
  const u16* gA[4];
#pragma unroll
  for (int rr = 0; rr < 4; rr++) {
    int row = m0 + rr * 64 + trow;
    if (row > kTOT - 1) row = kTOT - 1;
    gA[rr] = Xb + (size_t)row * kHID + cg * 8;
  }

  // ---- B staging (new): lane covers slot q of subtile s = w*16 + p*8 + (lane>>3) ----
  int q = lane & 7;
  int s0 = w * 16 + (lane >> 3);
  int kb0 = s0 >> 3, nb0 = s0 & 7;
  size_t wbase = (size_t)e * kHID * kINTER;
  const u16* gBg = Wgb + wbase + (size_t)(kb0 * 4 + (q >> 1)) * kINTER
                   + n0 + nb0 * 16 + (q & 1) * 8;
  const u16* gBu = Wub + wbase + (size_t)(kb0 * 4 + (q >> 1)) * kINTER
                   + n0 + nb0 * 16 + (q & 1) * 8;

  // ---- A fragment read offsets (verified R3) ----
  int abase = (wm + l15) * 64;
  int sz0 = ((quad ^ (l15 & 7)) << 3);
  int sz1 = (((4 | quad) ^ (l15 & 7)) << 3);

  // ---- B fragment tr-read base (byte): panel + quad*2048 + nb_base*128 + l15*8 ----
  u32 smb = lds_off(sm);
  u32 bgoff = quad * 2048 + (w & 1) * 512 + l15 * 8;

  f32x4 accg[4][4] = {};
  f32x4 accu[4][4] = {};

  auto stage = [&](int buf, int kt) {
    u16* Ab = sm + buf * 16384;
#pragma unroll
    for (int rr = 0; rr < 4; rr++)
      gll16(gA[rr] + (size_t)kt * 64, Ab + (rr * 64 + w * 8) * 64);
    u16* Bg = sm + 32768 + buf * 8192;
    u16* Bu = sm + 49152 + buf * 8192;
    const u16* pg = gBg + (size_t)kt * 64 * kINTER;
    const u16* pu = gBu + (size_t)kt * 64 * kINTER;
    gll16(pg, Bg + w * 1024);
    gll16(pg + (size_t)4 * kINTER, Bg + w * 1024 + 512);
    gll16(pu, Bu + w * 1024);
    gll16(pu + (size_t)4 * kINTER, Bu + w * 1024 + 512);
  };
  auto compute = [&](int buf) {
    const u16* A = sm + buf * 16384;
    u32 bg_base = smb + 65536 + buf * 16384 + bgoff;   // Bg panel (bytes)
    u32 bu_base = bg_base + 32768;                      // Bu panel
#pragma unroll
    for (int ks = 0; ks < 2; ks++) {
      int sz = ks ? sz1 : sz0;
      bf16x8 a[4];
#pragma unroll
      for (int i = 0; i < 4; i++) a[i] = *(const bf16x8*)(A + abase + i * 1024 + sz);
      u32x2 rg[4][2], ru[4][2];
#pragma unroll
      for (int j = 0; j < 4; j++) {
        u32 vg = bg_base + ks * 8192 + j * 128;
        rg[j][0] = trr<0>(vg); rg[j][1] = trr<1024>(vg);
        u32 vu = bu_base + ks * 8192 + j * 128;
        ru[j][0] = trr<0>(vu); ru[j][1] = trr<1024>(vu);
      }
      asm volatile("s_waitcnt lgkmcnt(0)" ::: "memory");
      __builtin_amdgcn_sched_barrier(0);
      bf16x8 bg[4], bu[4];
#pragma unroll
      for (int j = 0; j < 4; j++) {
        bg[j] = mkfrag(rg[j][0], rg[j][1]);
        bu[j] = mkfrag(ru[j][0], ru[j][1]);
      }
#pragma unroll
      for (int i = 0; i < 4; i++)
#pragma unroll
        for (int j = 0; j < 4; j++) {
          accg[i][j] = __builtin_amdgcn_mfma_f32_16x16x32_bf16(a[i], bg[j], accg[i][j], 0, 0, 0);
          accu[i][j] = __builtin_amdgcn_mfma_f32_16x16x32_bf16(a[i], bu[j], accu[i][j], 0, 0, 0);
        }
    }
  };

  constexpr int NK = kHID / 64;  // 32, even
  stage(0, 0);
  __syncthreads();
  for (int kt = 0; kt < NK; kt += 2) {
    stage(1, kt + 1);   // prefetch overlaps compute below
    compute(0);
    __syncthreads();
    if (kt + 2 < NK) stage(0, kt + 2);
    compute(1);
    __syncthreads();
  }

  // epilogue: h = silu(gate)*up*prob[row]. C/D layout: col=l15, row=quad*4+reg
#pragma unroll
  for (int i = 0; i < 4; i++) {
#pragma unroll
    for (int r = 0; r < 4; r++) {
      int row = m0 + wm + i * 16 + quad * 4 + r;
      if (row < m_end) {
        float p = probs[row];
#pragma unroll
        for (int j = 0; j < 4; j++) {
          int col = n0 + wn + j * 16 + l15;
          float g = accg[i][j][r], u = accu[i][j][r];
          float s = g / (1.0f + __expf(-g));
          H[(size_t)row * kINTER + col] = f2bf(s * u * p);
        }
      }
    }
  }
}

// ---------------- GEMM2: 256x128 tile, BK=64, 8 waves (4Mx2N) ----------------
// Same structure; B = w_down [INTER][HID] direct (rows HID-contiguous).
__launch_bounds__(512, 2)
__global__ void gemm2(const u16* __restrict__ H, const u16* __restrict__ Wdb,
                      const int* __restrict__ tpe, float* __restrict__ out) {
  __shared__ __align__(16) u16 sm[49152];  // 96 KB
  // u16 offsets: A0 0 | A1 16384 | B0 32768 | B1 40960

  int bx, by; map_block(bx, by);
  int e, m0, m_end;
  if (!expert_of_tile256(tpe, by, e, m0, m_end)) return;
  int n0 = bx * 128;

  int t = threadIdx.x;
  int w = t >> 6, lane = t & 63;
  int quad = lane >> 4, l15 = lane & 15;
  int wm = (w >> 1) * 64, wn = (w & 1) * 64;

  int trow = t >> 3;
  int cg = (t & 7) ^ (trow & 7);
  const u16* gA[4];
#pragma unroll
  for (int rr = 0; rr < 4; rr++) {
    int row = m0 + rr * 64 + trow;
    if (row > kTOT - 1) row = kTOT - 1;
    gA[rr] = H + (size_t)row * kINTER + cg * 8;
  }

  int q = lane & 7;
  int s0 = w * 16 + (lane >> 3);
  int kb0 = s0 >> 3, nb0 = s0 & 7;
  const u16* gB = Wdb + (size_t)e * kINTER * kHID
                  + (size_t)(kb0 * 4 + (q >> 1)) * kHID
                  + n0 + nb0 * 16 + (q & 1) * 8;

  int abase = (wm + l15) * 64;
  int sz0 = ((quad ^ (l15 & 7)) << 3);
  int sz1 = (((4 | quad) ^ (l15 & 7)) << 3);

  u32 smb = lds_off(sm);
  u32 boff = quad * 2048 + (w & 1) * 512 + l15 * 8;

  f32x4 acc[4][4] = {};

  auto stage = [&](int buf, int kt) {
    u16* Ab = sm + buf * 16384;
#pragma unroll
    for (int rr = 0; rr < 4; rr++)
      gll16(gA[rr] + (size_t)kt * 64, Ab + (rr * 64 + w * 8) * 64);
    u16* B = sm + 32768 + buf * 8192;
    const u16* pb = gB + (size_t)kt * 64 * kHID;
    gll16(pb, B + w * 1024);
    gll16(pb + (size_t)4 * kHID, B + w * 1024 + 512);
  };
  auto compute = [&](int buf) {
    const u16* A = sm + buf * 16384;
    u32 b_base = smb + 65536 + buf * 16384 + boff;
#pragma unroll
    for (int ks = 0; ks < 2; ks++) {
      int sz = ks ? sz1 : sz0;
      bf16x8 a[4];
#pragma unroll
      for (int i = 0; i < 4; i++) a[i] = *(const bf16x8*)(A + abase + i * 1024 + sz);
      u32x2 rb[4][2];
#pragma unroll
      for (int j = 0; j < 4; j++) {
        u32 vb = b_base + ks * 8192 + j * 128;
        rb[j][0] = trr<0>(vb); rb[j][1] = trr<1024>(vb);
      }
      asm volatile("s_waitcnt lgkmcnt(0)" ::: "memory");
      __builtin_amdgcn_sched_barrier(0);
      bf16x8 b[4];
#pragma unroll
      for (int j = 0; j < 4; j++) b[j] = mkfrag(rb[j][0], rb[j][1]);
#pragma unroll
      for (int i = 0; i < 4; i++)
#pragma unroll
        for (int j = 0; j < 4; j++)
          acc[i][j] = __builtin_amdgcn_mfma_f32_16x16x32_bf16(a[i], b[j], acc[i][j], 0, 0, 0);
    }
  };

  constexpr int NK = kINTER / 64;  // 22, even
  stage(0, 0);
  __syncthreads();
  for (int kt = 0; kt < NK; kt += 2) {
    stage(1, kt + 1);
    compute(0);
    __syncthreads();
    if (kt + 2 < NK) stage(0, kt + 2);
    compute(1);
    __syncthreads();
  }

#pragma unroll
  for (int i = 0; i < 4; i++) {
#pragma unroll
    for (int r = 0; r < 4; r++) {
      int row = m0 + wm + i * 16 + quad * 4 + r;
      if (row < m_end) {
#pragma unroll
        for (int j = 0; j < 4; j++) {
          int col = n0 + wn + j * 16 + l15;
          out[(size_t)row * kHID + col] = acc[i][j][r];
        }
      }
    }
  }
}

extern "C" void kernel_launch(void* const* d_in, const int* in_sizes, int n_in,
                              void* d_out, int out_size, void* d_ws, size_t ws_size,
                              hipStream_t stream) {
  const float* x = (const float*)d_in[0];
  const float* probs = (const float*)d_in[1];
  const float* wg = (const float*)d_in[2];
  const float* wu = (const float*)d_in[3];
  const float* wd = (const float*)d_in[4];
  const int* tpe = (const int*)d_in[5];
  float* out = (float*)d_out;

  // ws layout (u16 elements): Xb | Wg_b | Wu_b | Wd_b | H  (all bf16, W untransposed)
  u16* ws = (u16*)d_ws;
  u16* Xb = ws;
  u16* Wgb = Xb + (size_t)kTOT * kHID;
  u16* Wub = Wgb + (size_t)kE * kHID * kINTER;
  u16* Wdb = Wub + (size_t)kE * kHID * kINTER;
  u16* H = Wdb + (size_t)kE * kINTER * kHID;

  constexpr int kWE = kE * kHID * kINTER;  // 23,068,672 elems per weight tensor
  conv_bf16<<<(kTOT * kHID) / 2048, 256, 0, stream>>>(x, Xb);
  conv_bf16<<<kWE / 2048, 256, 0, stream>>>(wg, Wgb);
  conv_bf16<<<kWE / 2048, 256, 0, stream>>>(wu, Wub);
  conv_bf16<<<kWE / 2048, 256, 0, stream>>>(wd, Wdb);

  // 256-row supertiles: 32 full + up to 7 partials; extra blocks early-exit
  gemm1<<<dim3(kINTER / 128, 39), 512, 0, stream>>>(Xb, Wgb, Wub, probs, tpe, H);
  gemm2<<<dim3(kHID / 128, 39), 512, 0, stream>>>(H, Wdb, tpe, out);
}